// Round 9
// baseline (723.808 us; speedup 1.0000x reference)
//
#include <hip/hip_runtime.h>
#include <math.h>

#define S_LEN 512
#define CH 8

typedef float v2f __attribute__((ext_vector_type(2)));

__device__ __forceinline__ float fast_rcp(float x) { return __builtin_amdgcn_rcpf(x); }
__device__ __forceinline__ float fast_rsq(float x) { return __builtin_amdgcn_rsqf(x); }
__device__ __forceinline__ float exp2s(float x)    { return __builtin_amdgcn_exp2f(x); }
__device__ __forceinline__ v2f exp2v(v2f a) { return (v2f){exp2s(a.x), exp2s(a.y)}; }
__device__ __forceinline__ v2f rcpv(v2f a)  { return (v2f){fast_rcp(a.x), fast_rcp(a.y)}; }
__device__ __forceinline__ v2f rsqv(v2f a)  { return (v2f){fast_rsq(a.x), fast_rsq(a.y)}; }
__device__ __forceinline__ v2f maxv(v2f a, v2f b) { return __builtin_elementwise_max(a, b); }

// quad_perm DPP add (pure VALU)
template <int CTRL>
__device__ __forceinline__ float dpp_add(float v) {
    int vi = __builtin_bit_cast(int, v);
    int t  = __builtin_amdgcn_update_dpp(vi, vi, CTRL, 0xF, 0xF, true);
    return v + __builtin_bit_cast(float, t);
}

// wave-uniform broadcast of lane l's value (VALU v_readlane -> SGPR)
__device__ __forceinline__ float rl(float v, int l) {
    return __builtin_bit_cast(float, __builtin_amdgcn_readlane(__builtin_bit_cast(int, v), l));
}

// 2 independent waves/block; each wave owns one batch element; each thread
// packs points (lane, lane+64) in v2f. x is NOT staged in LDS: each 8-step
// chunk's 24 wave-uniform floats live one-per-lane in a single VGPR
// (double-buffered register prefetch), extracted per step via v_readlane.
// LDS = 3.3 KB -> thread-capped occupancy: 16 blocks/CU = 8 waves/SIMD.
__global__ __launch_bounds__(128, 8) void prnn_kernel(
    const float* __restrict__ x,
    const float* __restrict__ W1,
    const float* __restrict__ W2,
    float* __restrict__ out)
{
    const float MU      = (float)(3130.0 / 2.6);
    const float THREE_MU= (float)(3.0 * (3130.0 / 2.6));
    const float C43     = (float)(4.0 * (3130.0 / 2.6) / 3.0);
    const float C23     = (float)(2.0 * (3130.0 / 2.6) / 3.0);
    const float CP      = (float)(7825.0 / 3.0);
    const float Cf      = 0.003407f;
    const float K2      = (float)(1.4426950408889634 / 0.003407);  // log2(e)/C
    const float R3M     = (float)(1.0 / (3.0 * (3130.0 / 2.6)));
    const float AR3M    = (float)(64.8 / (3.0 * (3130.0 / 2.6)));
    const float L2B3MC  = 1.449290f;                               // log2(B/(3muC))
    const float LOG2E   = 1.4426950408889634f;
    const float LNI08   = (float)(0.8 * 0.6931471805599453);

    const int lane = threadIdx.x & 63;
    const int wv   = threadIdx.x >> 6;
    const int b    = blockIdx.x * 2 + wv;

    // Fold fc1 + elasticity into per-point deviatoric/pressure maps
    v2f D0[3], D1[3], D3[3], pv[3];
    #pragma unroll
    for (int f = 0; f < 3; ++f) {
        const int mA = lane, mB = lane + 64;
        v2f av = (v2f){ W1[(mA*3 + 0)*3 + f], W1[(mB*3 + 0)*3 + f] };
        v2f bv = (v2f){ W1[(mA*3 + 1)*3 + f], W1[(mB*3 + 1)*3 + f] };
        v2f cv = (v2f){ W1[(mA*3 + 2)*3 + f], W1[(mB*3 + 2)*3 + f] };
        D0[f] = C43*av - C23*bv;
        D1[f] = C43*bv - C23*av;
        D3[f] = MU*cv;
        pv[f] = CP*(av + bv);
    }
    v2f w2[3][3];
    #pragma unroll
    for (int o = 0; o < 3; ++o)
        #pragma unroll
        for (int j = 0; j < 3; ++j)
            w2[o][j] = (v2f){ W2[o*384 + lane*3 + j], W2[o*384 + (lane+64)*3 + j] };

    __shared__ float part[2][CH][3][17];     // 3.3 KB total

    const float* xb   = x   + (size_t)b * (S_LEN*3);
    float*       outb = out + (size_t)b * (S_LEN*3);

    // first chunk: lane i<24 holds x-chunk element i
    float vx_cur = (lane < 24) ? xb[lane] : 0.0f;

    v2f sp0 = (v2f){0.f,0.f}, sp1 = sp0, sp3 = sp0, kap = sp0;

    #pragma unroll 1
    for (int tc = 0; tc < S_LEN; tc += CH) {
        // register prefetch of the next chunk (wraps harmlessly on last iter)
        const int tn = (tc + CH < S_LEN) ? (tc + CH) : 0;
        float vx_nxt = (lane < 24) ? xb[tn*3 + lane] : 0.0f;

        #pragma unroll
        for (int tt = 0; tt < CH; ++tt) {
            const float x0 = rl(vx_cur, tt*3 + 0);
            const float x1 = rl(vx_cur, tt*3 + 1);
            const float x2 = rl(vx_cur, tt*3 + 2);

            // trial deviatoric stress + pressure
            v2f d0 = D0[0]*x0 + D0[1]*x1 + D0[2]*x2 - sp0;
            v2f d1 = D1[0]*x0 + D1[1]*x1 + D1[2]*x2 - sp1;
            v2f d3 = D3[0]*x0 + D3[1]*x1 + D3[2]*x2 - sp3;
            v2f p  = pv[0]*x0 + pv[1]*x1 + pv[2]*x2;

            // q^2 = 3(d0^2 + d1^2 + d0 d1 + d3^2)
            v2f h   = d0*d0 + d1*d1 + d0*d1 + d3*d3;
            v2f dot = maxv(3.0f*h, (v2f){1e-24f,1e-24f});
            v2f qi  = rsqv(dot);
            v2f q   = dot * qi;

            // dg = max(0, u0 + C*W(z)) — exact root of the return map
            v2f u0  = q*R3M - AR3M;
            v2f l2z = L2B3MC - (kap + u0)*K2;
            v2f z   = exp2v(l2z);
            v2f w   = maxv(LNI08*l2z, z*rcpv(1.0f + z));
            v2f y   = exp2v(w * LOG2E);
            v2f F   = w*y - z;
            v2f Fp  = w*y + y;
            v2f den = Fp*Fp + (F*y)*(-1.0f - 0.5f*w);
            w = w - (F*Fp)*rcpv(den);
            v2f dg  = maxv(u0 + Cf*w, (v2f){0.f,0.f});

            // radial return in stress space (exact no-op where dg==0)
            v2f t2 = THREE_MU*dg*qi;
            v2f u  = 1.0f - t2;
            sp0 += t2*d0; sp1 += t2*d1; sp3 += t2*d3;
            kap += dg;
            v2f r0 = u*d0 + p;
            v2f r1 = u*d1 + p;
            v2f r3 = u*d3;

            // fc2 contribution, pair-sum
            v2f a0 = w2[0][0]*r0 + w2[0][1]*r1 + w2[0][2]*r3;
            v2f a1 = w2[1][0]*r0 + w2[1][1]*r1 + w2[1][2]*r3;
            v2f a2 = w2[2][0]*r0 + w2[2][1]*r1 + w2[2][2]*r3;
            float c0 = a0.x + a0.y;
            float c1 = a1.x + a1.y;
            float c2 = a2.x + a2.y;

            // 4-lane reduce via DPP quad_perm (xor1=0xB1, xor2=0x4E)
            c0 = dpp_add<0xB1>(c0); c0 = dpp_add<0x4E>(c0);
            c1 = dpp_add<0xB1>(c1); c1 = dpp_add<0x4E>(c1);
            c2 = dpp_add<0xB1>(c2); c2 = dpp_add<0x4E>(c2);
            if ((lane & 3) == 0) {
                const int g = lane >> 2;     // 0..15
                part[wv][tt][0][g] = c0;
                part[wv][tt][1][g] = c1;
                part[wv][tt][2][g] = c2;
            }
        }
        // finish (same wave, DS program order — no barrier): lane r<24
        if (lane < 24) {
            const int rtt = lane / 3, ro = lane - rtt*3;
            float s = 0.0f;
            #pragma unroll
            for (int g = 0; g < 16; ++g) s += part[wv][rtt][ro][g];
            outb[tc*3 + lane] = s;
        }
        vx_cur = vx_nxt;
    }
}

extern "C" void kernel_launch(void* const* d_in, const int* in_sizes, int n_in,
                              void* d_out, int out_size, void* d_ws, size_t ws_size,
                              hipStream_t stream) {
    const float* x  = (const float*)d_in[0];
    const float* W1 = (const float*)d_in[1];
    const float* W2 = (const float*)d_in[2];
    float* out = (float*)d_out;
    prnn_kernel<<<2048, 128, 0, stream>>>(x, W1, W2, out);
}

// Round 10
// 412.958 us; speedup vs baseline: 1.7527x; 1.7527x over previous
//
#include <hip/hip_runtime.h>
#include <math.h>

#define S_LEN 512
#define CH 8      // finish/part granularity
#define XCH 32    // x-staging chunk (double-buffered in LDS)

typedef float v2f __attribute__((ext_vector_type(2)));

__device__ __forceinline__ float fast_rcp(float x) { return __builtin_amdgcn_rcpf(x); }
__device__ __forceinline__ float fast_rsq(float x) { return __builtin_amdgcn_rsqf(x); }
__device__ __forceinline__ float exp2s(float x)    { return __builtin_amdgcn_exp2f(x); }
__device__ __forceinline__ v2f exp2v(v2f a) { return (v2f){exp2s(a.x), exp2s(a.y)}; }
__device__ __forceinline__ v2f rcpv(v2f a)  { return (v2f){fast_rcp(a.x), fast_rcp(a.y)}; }
__device__ __forceinline__ v2f rsqv(v2f a)  { return (v2f){fast_rsq(a.x), fast_rsq(a.y)}; }
__device__ __forceinline__ v2f maxv(v2f a, v2f b) { return __builtin_elementwise_max(a, b); }

// quad_perm DPP add (pure VALU)
template <int CTRL>
__device__ __forceinline__ float dpp_add(float v) {
    int vi = __builtin_bit_cast(int, v);
    int t  = __builtin_amdgcn_update_dpp(vi, vi, CTRL, 0xF, 0xF, true);
    return v + __builtin_bit_cast(float, t);
}

// 2 independent waves/block; each wave owns one batch element; each thread
// packs points (lane, lane+64) in v2f. x staged per 32-step chunk in a
// double-buffered 1 KB/wave LDS region: global loads for chunk k+1 issued
// BEFORE computing chunk k, ds_write after (T14 split). LDS 5.3 KB ->
// thread-capped occupancy (8 waves/SIMD if VGPR<=64). bounds(128,6): VGPR
// cap 84 — R9 showed cap 64 spills this kernel to scratch.
__global__ __launch_bounds__(128, 6) void prnn_kernel(
    const float* __restrict__ x,
    const float* __restrict__ W1,
    const float* __restrict__ W2,
    float* __restrict__ out)
{
    const float MU      = (float)(3130.0 / 2.6);
    const float THREE_MU= (float)(3.0 * (3130.0 / 2.6));
    const float C43     = (float)(4.0 * (3130.0 / 2.6) / 3.0);
    const float C23     = (float)(2.0 * (3130.0 / 2.6) / 3.0);
    const float CP      = (float)(7825.0 / 3.0);
    const float Cf      = 0.003407f;
    const float K2      = (float)(1.4426950408889634 / 0.003407);  // log2(e)/C
    const float R3M     = (float)(1.0 / (3.0 * (3130.0 / 2.6)));
    const float AR3M    = (float)(64.8 / (3.0 * (3130.0 / 2.6)));
    const float L2B3MC  = 1.449290f;                               // log2(B/(3muC))
    const float LOG2E   = 1.4426950408889634f;
    const float LNI08   = (float)(0.8 * 0.6931471805599453);

    const int lane = threadIdx.x & 63;
    const int wv   = threadIdx.x >> 6;
    const int b    = blockIdx.x * 2 + wv;

    // Fold fc1 + elasticity into per-point deviatoric/pressure maps
    v2f D0[3], D1[3], D3[3], pv[3];
    #pragma unroll
    for (int f = 0; f < 3; ++f) {
        const int mA = lane, mB = lane + 64;
        v2f av = (v2f){ W1[(mA*3 + 0)*3 + f], W1[(mB*3 + 0)*3 + f] };
        v2f bv = (v2f){ W1[(mA*3 + 1)*3 + f], W1[(mB*3 + 1)*3 + f] };
        v2f cv = (v2f){ W1[(mA*3 + 2)*3 + f], W1[(mB*3 + 2)*3 + f] };
        D0[f] = C43*av - C23*bv;
        D1[f] = C43*bv - C23*av;
        D3[f] = MU*cv;
        pv[f] = CP*(av + bv);
    }
    v2f w2[3][3];
    #pragma unroll
    for (int o = 0; o < 3; ++o)
        #pragma unroll
        for (int j = 0; j < 3; ++j)
            w2[o][j] = (v2f){ W2[o*384 + lane*3 + j], W2[o*384 + (lane+64)*3 + j] };

    __shared__ float xs[2][2][XCH*4];        // [wave][buf][t*4+c], 2 KB
    __shared__ float part[2][CH][3][17];     // 3.3 KB

    const float* xb   = x   + (size_t)b * (S_LEN*3);
    float*       outb = out + (size_t)b * (S_LEN*3);

    // LDS write addresses for the 96 chunk elements: elem e -> (e/3)*4 + e%3
    const int e0 = lane;                 // all 64 lanes
    const int e1 = 64 + lane;            // lanes 0..31
    const int wa0 = (e0/3)*4 + e0%3;
    const int wa1 = (e1/3)*4 + e1%3;

    // prologue: stage chunk 0 into buf 0 (same wave writes, same wave reads)
    {
        float r0 = xb[e0];
        float r1 = (lane < 32) ? xb[e1] : 0.0f;
        xs[wv][0][wa0] = r0;
        if (lane < 32) xs[wv][0][wa1] = r1;
    }

    v2f sp0 = (v2f){0.f,0.f}, sp1 = sp0, sp3 = sp0, kap = sp0;
    int buf = 0;

    #pragma unroll 1
    for (int tc = 0; tc < S_LEN; tc += XCH) {
        // T14 issue-early: global loads for the next chunk (wraps harmlessly)
        const int tn = (tc + XCH < S_LEN) ? (tc + XCH) : 0;
        const float n0 = xb[tn*3 + e0];
        const float n1 = (lane < 32) ? xb[tn*3 + e1] : 0.0f;

        #pragma unroll 1
        for (int tt8 = 0; tt8 < XCH; tt8 += CH) {
            #pragma unroll
            for (int tt = 0; tt < CH; ++tt) {
                const int tl = tt8 + tt;
                const float x0 = xs[wv][buf][tl*4+0];
                const float x1 = xs[wv][buf][tl*4+1];
                const float x2 = xs[wv][buf][tl*4+2];

                // trial deviatoric stress + pressure
                v2f d0 = D0[0]*x0 + D0[1]*x1 + D0[2]*x2 - sp0;
                v2f d1 = D1[0]*x0 + D1[1]*x1 + D1[2]*x2 - sp1;
                v2f d3 = D3[0]*x0 + D3[1]*x1 + D3[2]*x2 - sp3;
                v2f p  = pv[0]*x0 + pv[1]*x1 + pv[2]*x2;

                // q^2 = 3(d0^2 + d1^2 + d0 d1 + d3^2)
                v2f h   = d0*d0 + d1*d1 + d0*d1 + d3*d3;
                v2f dot = maxv(3.0f*h, (v2f){1e-24f,1e-24f});
                v2f qi  = rsqv(dot);
                v2f q   = dot * qi;

                // dg = max(0, u0 + C*W(z)) — exact root of the return map
                v2f u0  = q*R3M - AR3M;
                v2f l2z = L2B3MC - (kap + u0)*K2;
                v2f z   = exp2v(l2z);
                v2f w   = maxv(LNI08*l2z, z*rcpv(1.0f + z));
                v2f y   = exp2v(w * LOG2E);
                v2f F   = w*y - z;
                v2f Fp  = w*y + y;
                v2f den = Fp*Fp + (F*y)*(-1.0f - 0.5f*w);
                w = w - (F*Fp)*rcpv(den);
                v2f dg  = maxv(u0 + Cf*w, (v2f){0.f,0.f});

                // radial return in stress space (exact no-op where dg==0)
                v2f t2 = THREE_MU*dg*qi;
                v2f u  = 1.0f - t2;
                sp0 += t2*d0; sp1 += t2*d1; sp3 += t2*d3;
                kap += dg;
                v2f r0 = u*d0 + p;
                v2f r1 = u*d1 + p;
                v2f r3 = u*d3;

                // fc2 contribution, pair-sum
                v2f a0 = w2[0][0]*r0 + w2[0][1]*r1 + w2[0][2]*r3;
                v2f a1 = w2[1][0]*r0 + w2[1][1]*r1 + w2[1][2]*r3;
                v2f a2 = w2[2][0]*r0 + w2[2][1]*r1 + w2[2][2]*r3;
                float c0 = a0.x + a0.y;
                float c1 = a1.x + a1.y;
                float c2 = a2.x + a2.y;

                // 4-lane reduce via DPP quad_perm (xor1=0xB1, xor2=0x4E)
                c0 = dpp_add<0xB1>(c0); c0 = dpp_add<0x4E>(c0);
                c1 = dpp_add<0xB1>(c1); c1 = dpp_add<0x4E>(c1);
                c2 = dpp_add<0xB1>(c2); c2 = dpp_add<0x4E>(c2);
                if ((lane & 3) == 0) {
                    const int g = lane >> 2;     // 0..15
                    part[wv][tt][0][g] = c0;
                    part[wv][tt][1][g] = c1;
                    part[wv][tt][2][g] = c2;
                }
            }
            // finish (same wave, DS program order — no barrier): lane r<24
            if (lane < 24) {
                const int rtt = lane / 3, ro = lane - rtt*3;
                float s = 0.0f;
                #pragma unroll
                for (int g = 0; g < 16; ++g) s += part[wv][rtt][ro][g];
                outb[(tc + tt8)*3 + lane] = s;
            }
        }
        // T14 write-late: stage the prefetched chunk into the other buffer
        xs[wv][buf^1][wa0] = n0;
        if (lane < 32) xs[wv][buf^1][wa1] = n1;
        buf ^= 1;
    }
}

extern "C" void kernel_launch(void* const* d_in, const int* in_sizes, int n_in,
                              void* d_out, int out_size, void* d_ws, size_t ws_size,
                              hipStream_t stream) {
    const float* x  = (const float*)d_in[0];
    const float* W1 = (const float*)d_in[1];
    const float* W2 = (const float*)d_in[2];
    float* out = (float*)d_out;
    prnn_kernel<<<2048, 128, 0, stream>>>(x, W1, W2, out);
}

// Round 11
// 404.246 us; speedup vs baseline: 1.7905x; 1.0216x over previous
//
#include <hip/hip_runtime.h>
#include <math.h>

#define S_LEN 512
#define CH 8

typedef float v2f __attribute__((ext_vector_type(2)));

__device__ __forceinline__ float fast_rcp(float x) { return __builtin_amdgcn_rcpf(x); }
__device__ __forceinline__ float fast_rsq(float x) { return __builtin_amdgcn_rsqf(x); }
__device__ __forceinline__ float exp2s(float x)    { return __builtin_amdgcn_exp2f(x); }
__device__ __forceinline__ v2f exp2v(v2f a) { return (v2f){exp2s(a.x), exp2s(a.y)}; }
__device__ __forceinline__ v2f rcpv(v2f a)  { return (v2f){fast_rcp(a.x), fast_rcp(a.y)}; }
__device__ __forceinline__ v2f rsqv(v2f a)  { return (v2f){fast_rsq(a.x), fast_rsq(a.y)}; }
__device__ __forceinline__ v2f maxv(v2f a, v2f b) { return __builtin_elementwise_max(a, b); }

// quad_perm DPP add (pure VALU)
template <int CTRL>
__device__ __forceinline__ float dpp_add(float v) {
    int vi = __builtin_bit_cast(int, v);
    int t  = __builtin_amdgcn_update_dpp(vi, vi, CTRL, 0xF, 0xF, true);
    return v + __builtin_bit_cast(float, t);
}

// R8 structure (grid-capped at 4 waves/SIMD -> keep full-sequence LDS staging;
// LDS is free). 2 independent waves/block, each owns one batch element; each
// thread packs points (lane, lane+64) in v2f. New in R11:
//  - Lambert-W series fast path (z <= 0.3, no trans) + R8 Halley slow path
//  - final-dev-stress recursion: d_t = M*dx_t + sd_{t-1}; sd = u*d
//  - ds_read_b128 for x
__global__ __launch_bounds__(128, 4) void prnn_kernel(
    const float* __restrict__ x,
    const float* __restrict__ W1,
    const float* __restrict__ W2,
    float* __restrict__ out)
{
    const float MU      = (float)(3130.0 / 2.6);
    const float THREE_MU= (float)(3.0 * (3130.0 / 2.6));
    const float C43     = (float)(4.0 * (3130.0 / 2.6) / 3.0);
    const float C23     = (float)(2.0 * (3130.0 / 2.6) / 3.0);
    const float CP      = (float)(7825.0 / 3.0);
    const float Cf      = 0.003407f;
    const float K2      = (float)(1.4426950408889634 / 0.003407);  // log2(e)/C
    const float R3M     = (float)(1.0 / (3.0 * (3130.0 / 2.6)));
    const float AR3M    = (float)(64.8 / (3.0 * (3130.0 / 2.6)));
    const float L2B3MC  = 1.449290f;                               // log2(B/(3muC))
    const float LOG2E   = 1.4426950408889634f;
    const float LNI08   = (float)(0.8 * 0.6931471805599453);
    const float C169    = (float)(16.0 / 9.0);

    const int lane = threadIdx.x & 63;
    const int wv   = threadIdx.x >> 6;
    const int b    = blockIdx.x * 2 + wv;

    // Fold fc1 + elasticity into per-point deviatoric/pressure maps
    v2f D0[3], D1[3], D3[3], pv[3];
    #pragma unroll
    for (int f = 0; f < 3; ++f) {
        const int mA = lane, mB = lane + 64;
        v2f av = (v2f){ W1[(mA*3 + 0)*3 + f], W1[(mB*3 + 0)*3 + f] };
        v2f bv = (v2f){ W1[(mA*3 + 1)*3 + f], W1[(mB*3 + 1)*3 + f] };
        v2f cv = (v2f){ W1[(mA*3 + 2)*3 + f], W1[(mB*3 + 2)*3 + f] };
        D0[f] = C43*av - C23*bv;
        D1[f] = C43*bv - C23*av;
        D3[f] = MU*cv;
        pv[f] = CP*(av + bv);
    }
    v2f w2[3][3];
    #pragma unroll
    for (int o = 0; o < 3; ++o)
        #pragma unroll
        for (int j = 0; j < 3; ++j)
            w2[o][j] = (v2f){ W2[o*384 + lane*3 + j], W2[o*384 + (lane+64)*3 + j] };

    __shared__ float4 xs4[2][S_LEN];         // padded stride-4, 16 KB
    __shared__ float  part[2][CH][3][17];    // 3.3 KB

    // Per-wave staging (no cross-wave sharing; same wave writes then reads ->
    // DS program order, no barrier)
    const float* xb = x + (size_t)b * (S_LEN*3);
    float* xsf = (float*)&xs4[wv][0];
    for (int i = lane; i < S_LEN*3; i += 64) {
        const int t = i / 3, c = i - 3*t;
        xsf[t*4 + c] = xb[i];
    }

    v2f sd0 = (v2f){0.f,0.f}, sd1 = sd0, sd3 = sd0, kap = sd0;
    float xp0 = 0.f, xp1 = 0.f, xp2 = 0.f;   // previous-step x
    float* outb = out + (size_t)b * (S_LEN*3);

    #pragma unroll 1
    for (int tc = 0; tc < S_LEN; tc += CH) {
        #pragma unroll
        for (int tt = 0; tt < CH; ++tt) {
            const int t = tc + tt;
            const float4 xv = xs4[wv][t];            // one ds_read_b128
            const float x0 = xv.x, x1 = xv.y, x2 = xv.z;
            const float dx0 = x0 - xp0, dx1 = x1 - xp1, dx2 = x2 - xp2;
            xp0 = x0; xp1 = x1; xp2 = x2;

            // trial deviatoric stress: d = M*dx + sd_prev; pressure from abs x
            v2f d0 = D0[0]*dx0 + D0[1]*dx1 + D0[2]*dx2 + sd0;
            v2f d1 = D1[0]*dx0 + D1[1]*dx1 + D1[2]*dx2 + sd1;
            v2f d3 = D3[0]*dx0 + D3[1]*dx1 + D3[2]*dx2 + sd3;
            v2f p  = pv[0]*x0 + pv[1]*x1 + pv[2]*x2;

            // q^2 = 3(d0^2 + d1^2 + d0 d1 + d3^2)   [d2 = -(d0+d1)]
            v2f h   = d0*d0 + d1*d1 + d0*d1 + d3*d3;
            v2f dot = maxv(3.0f*h, (v2f){1e-24f,1e-24f});
            v2f qi  = rsqv(dot);
            v2f q   = dot * qi;

            // dg = max(0, u0 + C*W(z)); z <= ~522 structurally
            v2f u0  = q*R3M - AR3M;
            v2f l2z = L2B3MC - (kap + u0)*K2;
            v2f z   = exp2v(l2z);

            v2f w;
            if (__any((z.x > 0.3f) || (z.y > 0.3f))) {
                // slow path (rare, spin-up): R8 init + one Halley step
                w = maxv(LNI08*l2z, z*rcpv(1.0f + z));
                v2f y   = exp2v(w * LOG2E);
                v2f F   = w*y - z;
                v2f Fp  = w*y + y;
                v2f den = Fp*Fp + (F*y)*(-1.0f - 0.5f*w);
                w = w - (F*Fp)*rcpv(den);
            } else {
                // series: W(z) = z(1 - z(1 - 1.5z(1 - (16/9)z))), |err|<=0.013
                v2f t1 = 1.0f - C169*z;
                v2f m  = 1.5f*z;
                v2f t2s= 1.0f - m*t1;
                v2f t3 = 1.0f - z*t2s;
                w = z*t3;
            }
            v2f dg  = maxv(u0 + Cf*w, (v2f){0.f,0.f});

            // radial return: sd = u*d (final deviatoric stress = next state)
            v2f t2 = THREE_MU*dg*qi;
            v2f u  = 1.0f - t2;
            sd0 = u*d0; sd1 = u*d1; sd3 = u*d3;
            kap += dg;
            v2f r0 = sd0 + p;
            v2f r1 = sd1 + p;

            // fc2 contribution, pair-sum
            v2f a0 = w2[0][0]*r0 + w2[0][1]*r1 + w2[0][2]*sd3;
            v2f a1 = w2[1][0]*r0 + w2[1][1]*r1 + w2[1][2]*sd3;
            v2f a2 = w2[2][0]*r0 + w2[2][1]*r1 + w2[2][2]*sd3;
            float c0 = a0.x + a0.y;
            float c1 = a1.x + a1.y;
            float c2 = a2.x + a2.y;

            // 4-lane reduce via DPP quad_perm (xor1=0xB1, xor2=0x4E)
            c0 = dpp_add<0xB1>(c0); c0 = dpp_add<0x4E>(c0);
            c1 = dpp_add<0xB1>(c1); c1 = dpp_add<0x4E>(c1);
            c2 = dpp_add<0xB1>(c2); c2 = dpp_add<0x4E>(c2);
            if ((lane & 3) == 0) {
                const int g = lane >> 2;     // 0..15
                part[wv][tt][0][g] = c0;
                part[wv][tt][1][g] = c1;
                part[wv][tt][2][g] = c2;
            }
        }
        // finish (same wave, DS program order — no barrier): lane r<24
        if (lane < 24) {
            const int rtt = lane / 3, ro = lane - rtt*3;
            float s = 0.0f;
            #pragma unroll
            for (int g = 0; g < 16; ++g) s += part[wv][rtt][ro][g];
            outb[tc*3 + lane] = s;
        }
    }
}

extern "C" void kernel_launch(void* const* d_in, const int* in_sizes, int n_in,
                              void* d_out, int out_size, void* d_ws, size_t ws_size,
                              hipStream_t stream) {
    const float* x  = (const float*)d_in[0];
    const float* W1 = (const float*)d_in[1];
    const float* W2 = (const float*)d_in[2];
    float* out = (float*)d_out;
    prnn_kernel<<<2048, 128, 0, stream>>>(x, W1, W2, out);
}

// Round 12
// 356.496 us; speedup vs baseline: 2.0303x; 1.1339x over previous
//
#include <hip/hip_runtime.h>
#include <math.h>

#define S_LEN 512
#define CH 8

typedef float v2f __attribute__((ext_vector_type(2)));

__device__ __forceinline__ float fast_rcp(float x) { return __builtin_amdgcn_rcpf(x); }
__device__ __forceinline__ float fast_rsq(float x) { return __builtin_amdgcn_rsqf(x); }
__device__ __forceinline__ float exp2s(float x)    { return __builtin_amdgcn_exp2f(x); }
__device__ __forceinline__ v2f exp2v(v2f a) { return (v2f){exp2s(a.x), exp2s(a.y)}; }
__device__ __forceinline__ v2f rcpv(v2f a)  { return (v2f){fast_rcp(a.x), fast_rcp(a.y)}; }
__device__ __forceinline__ v2f rsqv(v2f a)  { return (v2f){fast_rsq(a.x), fast_rsq(a.y)}; }
__device__ __forceinline__ v2f maxv(v2f a, v2f b) { return __builtin_elementwise_max(a, b); }

// quad_perm DPP add (pure VALU)
template <int CTRL>
__device__ __forceinline__ float dpp_add(float v) {
    int vi = __builtin_bit_cast(int, v);
    int t  = __builtin_amdgcn_update_dpp(vi, vi, CTRL, 0xF, 0xF, true);
    return v + __builtin_bit_cast(float, t);
}

// R8 structure: 2 independent waves/block, each owns one batch element; each
// thread packs points (lane, lane+64) in v2f; full-sequence x in per-wave LDS;
// barrier-free (per-wave LDS, DS program order). R12: branchless Halley W
// (cheap init, no rcp), pressure folded into a startup 3x3 G applied in the
// finish block, kappa state kept in log2-domain.
__global__ __launch_bounds__(128, 4) void prnn_kernel(
    const float* __restrict__ x,
    const float* __restrict__ W1,
    const float* __restrict__ W2,
    float* __restrict__ out)
{
    const double MUd = 3130.0 / 2.6;
    const double Cd  = 0.003407;
    const double K2d = 1.4426950408889634 / Cd;          // log2(e)/C
    const float MU      = (float)MUd;
    const float THREE_MU= (float)(3.0 * MUd);
    const float C43     = (float)(4.0 * MUd / 3.0);
    const float C23     = (float)(2.0 * MUd / 3.0);
    const float CP      = (float)(7825.0 / 3.0);
    const float Cf      = (float)Cd;
    const float R3M     = (float)(1.0 / (3.0 * MUd));
    const float AR3M    = (float)(64.8 / (3.0 * MUd));
    const float MQ      = (float)(-K2d / (3.0 * MUd));   // -R3M*K2
    const float KA0     = (float)(1.4492898 + (64.8 / (3.0 * MUd)) * K2d); // L2B3MC + AR3M*K2
    const float K2      = (float)K2d;
    const float LOG2E   = 1.4426950408889634f;
    const float LN08    = (float)(0.8 * 0.6931471805599453);  // 0.8*ln2

    const int lane = threadIdx.x & 63;
    const int wv   = threadIdx.x >> 6;
    const int b    = blockIdx.x * 2 + wv;

    // Fold fc1 + elasticity into per-point deviatoric map + pressure row
    v2f D0[3], D1[3], D3[3], pv[3];
    #pragma unroll
    for (int f = 0; f < 3; ++f) {
        const int mA = lane, mB = lane + 64;
        v2f av = (v2f){ W1[(mA*3 + 0)*3 + f], W1[(mB*3 + 0)*3 + f] };
        v2f bv = (v2f){ W1[(mA*3 + 1)*3 + f], W1[(mB*3 + 1)*3 + f] };
        v2f cv = (v2f){ W1[(mA*3 + 2)*3 + f], W1[(mB*3 + 2)*3 + f] };
        D0[f] = C43*av - C23*bv;
        D1[f] = C43*bv - C23*av;
        D3[f] = MU*cv;
        pv[f] = CP*(av + bv);
    }
    v2f w2[3][3];
    #pragma unroll
    for (int o = 0; o < 3; ++o)
        #pragma unroll
        for (int j = 0; j < 3; ++j)
            w2[o][j] = (v2f){ W2[o*384 + lane*3 + j], W2[o*384 + (lane+64)*3 + j] };

    // Startup: G[o][f] = sum_m (w2[o][0]+w2[o][1])[m] * pv[f][m]  (per-wave 3x3)
    // via butterfly all-reduce; then select row ro = lane%3 for the finish.
    float gsel0, gsel1, gsel2;
    {
        v2f w2s[3];
        #pragma unroll
        for (int o = 0; o < 3; ++o) w2s[o] = w2[o][0] + w2[o][1];
        float G[3][3];
        #pragma unroll
        for (int o = 0; o < 3; ++o)
            #pragma unroll
            for (int f = 0; f < 3; ++f) {
                v2f gv = w2s[o] * pv[f];
                float g = gv.x + gv.y;
                #pragma unroll
                for (int m = 1; m < 64; m <<= 1) g += __shfl_xor(g, m, 64);
                G[o][f] = g;
            }
        const int ro = lane % 3;
        gsel0 = (ro == 0) ? G[0][0] : (ro == 1) ? G[1][0] : G[2][0];
        gsel1 = (ro == 0) ? G[0][1] : (ro == 1) ? G[1][1] : G[2][1];
        gsel2 = (ro == 0) ? G[0][2] : (ro == 1) ? G[1][2] : G[2][2];
    }

    __shared__ float4 xs4[2][S_LEN];         // 16 KB
    __shared__ float  part[2][CH][3][17];    // 3.3 KB

    const float* xb = x + (size_t)b * (S_LEN*3);
    float* xsf = (float*)&xs4[wv][0];
    for (int i = lane; i < S_LEN*3; i += 64) {
        const int t = i / 3, c = i - 3*t;
        xsf[t*4 + c] = xb[i];
    }

    v2f sd0 = (v2f){0.f,0.f}, sd1 = sd0, sd3 = sd0;
    v2f ka2 = (v2f){KA0, KA0};               // KA0 - kappa*K2
    float xp0 = 0.f, xp1 = 0.f, xp2 = 0.f;
    float* outb = out + (size_t)b * (S_LEN*3);

    #pragma unroll 1
    for (int tc = 0; tc < S_LEN; tc += CH) {
        #pragma unroll
        for (int tt = 0; tt < CH; ++tt) {
            const int t = tc + tt;
            const float4 xv = xs4[wv][t];
            const float dx0 = xv.x - xp0, dx1 = xv.y - xp1, dx2 = xv.z - xp2;
            xp0 = xv.x; xp1 = xv.y; xp2 = xv.z;

            // trial deviatoric stress: d = M*dx + sd_prev
            v2f d0 = D0[0]*dx0 + D0[1]*dx1 + D0[2]*dx2 + sd0;
            v2f d1 = D1[0]*dx0 + D1[1]*dx1 + D1[2]*dx2 + sd1;
            v2f d3 = D3[0]*dx0 + D3[1]*dx1 + D3[2]*dx2 + sd3;

            // q^2 = 3(d0^2 + d1^2 + d0 d1 + d3^2)   [d2 = -(d0+d1)]
            v2f h   = d0*d0 + d1*d1 + d0*d1 + d3*d3;
            v2f dot = maxv(3.0f*h, (v2f){1e-24f,1e-24f});
            v2f qi  = rsqv(dot);
            v2f q   = dot * qi;

            // dg = max(0, u0 + C*W(z));  l2z = KA0 - (kap+u0)*K2 via ka2 state
            v2f u0  = q*R3M - AR3M;
            v2f l2z = q*MQ + ka2;
            v2f z   = exp2v(l2z);

            // Halley on F = w e^w - z; init = max(0.8 ln z, z - z^2) (one-sided)
            v2f w   = maxv(LN08*l2z, z*(1.0f - z));
            v2f y   = exp2v(w * LOG2E);
            v2f g   = w*y;
            v2f F   = g - z;
            v2f Fp  = g + y;
            v2f m   = (F*y)*(2.0f + w);
            v2f den = Fp*Fp - 0.5f*m;
            w = w - (F*Fp)*rcpv(den);

            v2f dg  = maxv(u0 + Cf*w, (v2f){0.f,0.f});

            // radial return: sd = (1 - 3mu*dg/q) * d; ka2 -= K2*dg
            v2f n3q = -THREE_MU*qi;
            v2f u   = dg*n3q + 1.0f;
            sd0 = u*d0; sd1 = u*d1; sd3 = u*d3;
            ka2 = ka2 - K2*dg;

            // fc2 on deviatoric part only (pressure handled by G in finish)
            v2f a0 = w2[0][0]*sd0 + w2[0][1]*sd1 + w2[0][2]*sd3;
            v2f a1 = w2[1][0]*sd0 + w2[1][1]*sd1 + w2[1][2]*sd3;
            v2f a2 = w2[2][0]*sd0 + w2[2][1]*sd1 + w2[2][2]*sd3;
            float c0 = a0.x + a0.y;
            float c1 = a1.x + a1.y;
            float c2 = a2.x + a2.y;

            // 4-lane reduce via DPP quad_perm (xor1=0xB1, xor2=0x4E)
            c0 = dpp_add<0xB1>(c0); c0 = dpp_add<0x4E>(c0);
            c1 = dpp_add<0xB1>(c1); c1 = dpp_add<0x4E>(c1);
            c2 = dpp_add<0xB1>(c2); c2 = dpp_add<0x4E>(c2);
            if ((lane & 3) == 0) {
                const int g16 = lane >> 2;   // 0..15
                part[wv][tt][0][g16] = c0;
                part[wv][tt][1][g16] = c1;
                part[wv][tt][2][g16] = c2;
            }
        }
        // finish (same wave, DS program order): lane r<24 -> (tt=r/3, o=r%3);
        // add the pressure path G[o]·x(t) here.
        if (lane < 24) {
            const int rtt = lane / 3;
            float s = 0.0f;
            #pragma unroll
            for (int g16 = 0; g16 < 16; ++g16) s += part[wv][rtt][lane - rtt*3][g16];
            const float4 xf = xs4[wv][tc + rtt];
            s = __builtin_fmaf(gsel0, xf.x, s);
            s = __builtin_fmaf(gsel1, xf.y, s);
            s = __builtin_fmaf(gsel2, xf.z, s);
            outb[tc*3 + lane] = s;
        }
    }
}

extern "C" void kernel_launch(void* const* d_in, const int* in_sizes, int n_in,
                              void* d_out, int out_size, void* d_ws, size_t ws_size,
                              hipStream_t stream) {
    const float* x  = (const float*)d_in[0];
    const float* W1 = (const float*)d_in[1];
    const float* W2 = (const float*)d_in[2];
    float* out = (float*)d_out;
    prnn_kernel<<<2048, 128, 0, stream>>>(x, W1, W2, out);
}

// Round 13
// 306.983 us; speedup vs baseline: 2.3578x; 1.1613x over previous
//
#include <hip/hip_runtime.h>
#include <math.h>

#define S_LEN 512
#define CH 8
#define NSEG 128
#define TBL_L0 -22.0f
#define TBL_INVH 4.0f
#define TBL_H 0.25f

typedef float v2f __attribute__((ext_vector_type(2)));

__device__ __forceinline__ float fast_rcp(float x) { return __builtin_amdgcn_rcpf(x); }
__device__ __forceinline__ float fast_rsq(float x) { return __builtin_amdgcn_rsqf(x); }
__device__ __forceinline__ float exp2s(float x)    { return __builtin_amdgcn_exp2f(x); }
__device__ __forceinline__ v2f rsqv(v2f a)  { return (v2f){fast_rsq(a.x), fast_rsq(a.y)}; }
__device__ __forceinline__ v2f maxv(v2f a, v2f b) { return __builtin_elementwise_max(a, b); }

// quad_perm DPP add (pure VALU)
template <int CTRL>
__device__ __forceinline__ float dpp_add(float v) {
    int vi = __builtin_bit_cast(int, v);
    int t  = __builtin_amdgcn_update_dpp(vi, vi, CTRL, 0xF, 0xF, true);
    return v + __builtin_bit_cast(float, t);
}

// R12 structure (2 independent waves/block, v2f point-pairs, barrier-free main
// loop, pressure folded into startup G). R13: the Lambert-W Halley solve is
// replaced by a 128-segment piecewise-linear table of C*W(2^l2z) in l2z,
// built once per block. Per-step trans ops drop 8 -> 2 (rsq only).
__global__ __launch_bounds__(128, 4) void prnn_kernel(
    const float* __restrict__ x,
    const float* __restrict__ W1,
    const float* __restrict__ W2,
    float* __restrict__ out)
{
    const double MUd = 3130.0 / 2.6;
    const double Cd  = 0.003407;
    const double K2d = 1.4426950408889634 / Cd;          // log2(e)/C
    const float MU      = (float)MUd;
    const float THREE_MU= (float)(3.0 * MUd);
    const float C43     = (float)(4.0 * MUd / 3.0);
    const float C23     = (float)(2.0 * MUd / 3.0);
    const float CP      = (float)(7825.0 / 3.0);
    const float Cf      = (float)Cd;
    const float R3M     = (float)(1.0 / (3.0 * MUd));
    const float AR3M    = (float)(64.8 / (3.0 * MUd));
    const float MQ      = (float)(-K2d / (3.0 * MUd));   // -R3M*K2
    const float KA0     = (float)(1.4492898 + (64.8 / (3.0 * MUd)) * K2d);
    const float K2      = (float)K2d;
    const float LOG2E   = 1.4426950408889634f;
    const float LN08    = (float)(0.8 * 0.6931471805599453);

    const int tid  = threadIdx.x;
    const int lane = tid & 63;
    const int wv   = tid >> 6;
    const int b    = blockIdx.x * 2 + wv;

    __shared__ float2 xs01[2][S_LEN];        // (x0,x1), 8 KB
    __shared__ float  xs2g[2][S_LEN];        // x2, 4 KB
    __shared__ float  part[2][CH][3][17];    // 3.3 KB
    __shared__ float2 wtab[NSEG];            // (slope, intercept) of C*W, 1 KB

    // ---- build C*W(2^l2z) PWL table (block-shared, startup only) ----
    {
        float wn = 0.0f;
        if (tid <= NSEG) {
            const float s = TBL_L0 + (float)tid * TBL_H;
            const float z = exp2s(s);
            float w = fmaxf(LN08 * s, z * (1.0f - z));
            #pragma unroll
            for (int it = 0; it < 4; ++it) {
                const float y   = exp2s(w * LOG2E);
                const float g   = w * y;
                const float F   = g - z;
                const float Fp  = g + y;
                const float den = Fp*Fp - 0.5f*((F*y)*(2.0f + w));
                w = w - (F*Fp)*fast_rcp(den);
            }
            wn = w;
            ((float*)wtab)[tid] = wn;        // nodes parked as floats
        }
        __syncthreads();
        float wnext = 0.0f;
        if (tid < NSEG) wnext = ((float*)wtab)[tid + 1];
        __syncthreads();
        if (tid < NSEG) {
            const float sl = (wnext - wn) * (Cf * TBL_INVH);
            const float bi = Cf * wn - sl * (TBL_L0 + (float)tid * TBL_H);
            wtab[tid] = (float2){sl, bi};
        }
        __syncthreads();
    }

    // Fold fc1 + elasticity into per-point deviatoric map + pressure row
    v2f D0[3], D1[3], D3[3], pv[3];
    #pragma unroll
    for (int f = 0; f < 3; ++f) {
        const int mA = lane, mB = lane + 64;
        v2f av = (v2f){ W1[(mA*3 + 0)*3 + f], W1[(mB*3 + 0)*3 + f] };
        v2f bv = (v2f){ W1[(mA*3 + 1)*3 + f], W1[(mB*3 + 1)*3 + f] };
        v2f cv = (v2f){ W1[(mA*3 + 2)*3 + f], W1[(mB*3 + 2)*3 + f] };
        D0[f] = C43*av - C23*bv;
        D1[f] = C43*bv - C23*av;
        D3[f] = MU*cv;
        pv[f] = CP*(av + bv);
    }
    v2f w2[3][3];
    #pragma unroll
    for (int o = 0; o < 3; ++o)
        #pragma unroll
        for (int j = 0; j < 3; ++j)
            w2[o][j] = (v2f){ W2[o*384 + lane*3 + j], W2[o*384 + (lane+64)*3 + j] };

    // Startup G (pressure fold): G[o][f] = sum_m (w2[o][0]+w2[o][1])[m]*pv[f][m]
    float gsel0, gsel1, gsel2;
    {
        v2f w2s[3];
        #pragma unroll
        for (int o = 0; o < 3; ++o) w2s[o] = w2[o][0] + w2[o][1];
        float G[3][3];
        #pragma unroll
        for (int o = 0; o < 3; ++o)
            #pragma unroll
            for (int f = 0; f < 3; ++f) {
                v2f gv = w2s[o] * pv[f];
                float g = gv.x + gv.y;
                #pragma unroll
                for (int m = 1; m < 64; m <<= 1) g += __shfl_xor(g, m, 64);
                G[o][f] = g;
            }
        const int ro = lane % 3;
        gsel0 = (ro == 0) ? G[0][0] : (ro == 1) ? G[1][0] : G[2][0];
        gsel1 = (ro == 0) ? G[0][1] : (ro == 1) ? G[1][1] : G[2][1];
        gsel2 = (ro == 0) ? G[0][2] : (ro == 1) ? G[1][2] : G[2][2];
    }

    // Per-wave x staging (same wave writes then reads -> DS program order)
    const float* xb = x + (size_t)b * (S_LEN*3);
    for (int i = lane; i < S_LEN; i += 64) {
        xs01[wv][i] = (float2){ xb[i*3 + 0], xb[i*3 + 1] };
        xs2g[wv][i] = xb[i*3 + 2];
    }

    v2f sd0 = (v2f){0.f,0.f}, sd1 = sd0, sd3 = sd0;
    v2f ka2 = (v2f){KA0, KA0};
    float xp0 = 0.f, xp1 = 0.f, xp2 = 0.f;
    float* outb = out + (size_t)b * (S_LEN*3);

    #pragma unroll 1
    for (int tc = 0; tc < S_LEN; tc += CH) {
        #pragma unroll
        for (int tt = 0; tt < CH; ++tt) {
            const int t = tc + tt;
            const float2 x01 = xs01[wv][t];
            const float  xv2 = xs2g[wv][t];
            const float dx0 = x01.x - xp0, dx1 = x01.y - xp1, dx2 = xv2 - xp2;
            xp0 = x01.x; xp1 = x01.y; xp2 = xv2;

            // trial deviatoric stress: d = M*dx + sd_prev
            v2f d0 = D0[0]*dx0 + D0[1]*dx1 + D0[2]*dx2 + sd0;
            v2f d1 = D1[0]*dx0 + D1[1]*dx1 + D1[2]*dx2 + sd1;
            v2f d3 = D3[0]*dx0 + D3[1]*dx1 + D3[2]*dx2 + sd3;

            // q^2 = 3(d0^2 + d1^2 + d0 d1 + d3^2)   [d2 = -(d0+d1)]
            v2f h   = d0*d0 + d1*d1 + d0*d1 + d3*d3;
            v2f dot = maxv(3.0f*h, (v2f){1e-24f,1e-24f});
            v2f qi  = rsqv(dot);
            v2f q   = dot * qi;

            // dg = max(0, u0 + C*W(2^l2z)) via PWL table in l2z
            v2f u0  = q*R3M - AR3M;
            v2f l2z = q*MQ + ka2;

            const float fix = __builtin_fmaf(l2z.x, TBL_INVH, -TBL_L0*TBL_INVH);
            const float fiy = __builtin_fmaf(l2z.y, TBL_INVH, -TBL_L0*TBL_INVH);
            int ix = (int)fix; ix = ix < 0 ? 0 : (ix > NSEG-1 ? NSEG-1 : ix);
            int iy = (int)fiy; iy = iy < 0 ? 0 : (iy > NSEG-1 ? NSEG-1 : iy);
            const float2 tx = wtab[ix];
            const float2 ty = wtab[iy];
            v2f cw = (v2f){ __builtin_fmaf(tx.x, l2z.x, tx.y),
                            __builtin_fmaf(ty.x, l2z.y, ty.y) };
            v2f dg = maxv(u0 + cw, (v2f){0.f,0.f});

            // radial return: sd = (1 - 3mu*dg/q)*d; ka2 -= K2*dg
            v2f n3q = -THREE_MU*qi;
            v2f u   = dg*n3q + 1.0f;
            sd0 = u*d0; sd1 = u*d1; sd3 = u*d3;
            ka2 = ka2 - K2*dg;

            // fc2 on deviatoric part (pressure via G in finish)
            v2f a0 = w2[0][0]*sd0 + w2[0][1]*sd1 + w2[0][2]*sd3;
            v2f a1 = w2[1][0]*sd0 + w2[1][1]*sd1 + w2[1][2]*sd3;
            v2f a2 = w2[2][0]*sd0 + w2[2][1]*sd1 + w2[2][2]*sd3;
            float c0 = a0.x + a0.y;
            float c1 = a1.x + a1.y;
            float c2 = a2.x + a2.y;

            // 4-lane reduce via DPP quad_perm
            c0 = dpp_add<0xB1>(c0); c0 = dpp_add<0x4E>(c0);
            c1 = dpp_add<0xB1>(c1); c1 = dpp_add<0x4E>(c1);
            c2 = dpp_add<0xB1>(c2); c2 = dpp_add<0x4E>(c2);
            if ((lane & 3) == 0) {
                const int g16 = lane >> 2;
                part[wv][tt][0][g16] = c0;
                part[wv][tt][1][g16] = c1;
                part[wv][tt][2][g16] = c2;
            }
        }
        // finish (same wave, DS program order): lane r<24 -> (tt=r/3, o=r%3)
        if (lane < 24) {
            const int rtt = lane / 3;
            float s = 0.0f;
            #pragma unroll
            for (int g16 = 0; g16 < 16; ++g16) s += part[wv][rtt][lane - rtt*3][g16];
            const float2 xf01 = xs01[wv][tc + rtt];
            const float  xf2  = xs2g[wv][tc + rtt];
            s = __builtin_fmaf(gsel0, xf01.x, s);
            s = __builtin_fmaf(gsel1, xf01.y, s);
            s = __builtin_fmaf(gsel2, xf2,    s);
            outb[tc*3 + lane] = s;
        }
    }
}

extern "C" void kernel_launch(void* const* d_in, const int* in_sizes, int n_in,
                              void* d_out, int out_size, void* d_ws, size_t ws_size,
                              hipStream_t stream) {
    const float* x  = (const float*)d_in[0];
    const float* W1 = (const float*)d_in[1];
    const float* W2 = (const float*)d_in[2];
    float* out = (float*)d_out;
    prnn_kernel<<<2048, 128, 0, stream>>>(x, W1, W2, out);
}